// Round 6
// baseline (4520.119 us; speedup 1.0000x reference)
//
#include <hip/hip_runtime.h>
#include <hip/hip_bf16.h>
#include <stdint.h>
#include <math.h>

// POD_GalerkinTransformer forward, MI355X (gfx950).
// Split-split bf16 MFMA GEMMs (A,B hi/lo pairs, 3 MFMAs/acc ~ fp32 products),
// 128x128 tile, BK=32, 4-tile double-buffered 64KiB LDS. InstanceNorm fused
// into qkv epilogue. Attention consumes hi/lo-reconstructed f32.
// Layers processed in TWO half-batches to keep total workspace ~213MB
// (ws_size appears to be 256MiB; R3/R4/R5 aborts were ws overflows).

typedef __hip_bfloat16 bf16;
typedef __bf16 bf16x8 __attribute__((ext_vector_type(8)));
typedef float f32x4 __attribute__((ext_vector_type(4)));
typedef unsigned short u16x8 __attribute__((ext_vector_type(8)));

#define SEQ 4096
#define NTOK 16384
#define HTOK 8192
#define HID 512

__device__ __forceinline__ float wred(float x) {
#pragma unroll
  for (int off = 32; off; off >>= 1) x += __shfl_xor(x, off);
  return x;
}

__device__ __forceinline__ unsigned short f2b(float v) {
  __hip_bfloat16 h = __float2bfloat16(v);
  return __builtin_bit_cast(unsigned short, h);
}

__device__ __forceinline__ float b2f(unsigned short u) {
  unsigned int x = ((unsigned int)u) << 16;
  return __builtin_bit_cast(float, x);
}

__device__ __forceinline__ void gload16(const void* g, void* l) {
  __builtin_amdgcn_global_load_lds(
      reinterpret_cast<const __attribute__((address_space(1))) int*>(
          reinterpret_cast<uintptr_t>(g)),
      reinterpret_cast<__attribute__((address_space(3))) int*>(
          reinterpret_cast<uintptr_t>(l)),
      16, 0, 0);
}

// ------- weight transpose+cast: [D][K][N] f32 -> [D][N][K] bf16 hi/lo ------
__global__ __launch_bounds__(256) void k_transpose(const float* __restrict__ src,
                                                   bf16* __restrict__ dhi,
                                                   bf16* __restrict__ dlo,
                                                   int K, int N) {
  int d = blockIdx.z;
  const float* s = src + (size_t)d * K * N;
  bf16* ohi = dhi + (size_t)d * N * K;
  bf16* olo = dlo + (size_t)d * N * K;
  int k0 = blockIdx.x * 64, n0 = blockIdx.y * 64;
  __shared__ float tile[64][65];
  int t = threadIdx.x, c = t & 63, r4 = t >> 6;
#pragma unroll
  for (int i = 0; i < 16; ++i) {
    int r = i * 4 + r4;
    tile[r][c] = s[(size_t)(k0 + r) * N + n0 + c];
  }
  __syncthreads();
#pragma unroll
  for (int i = 0; i < 16; ++i) {
    int r = i * 4 + r4;
    float v = tile[c][r];
    bf16 hi = __float2bfloat16(v);
    float lo = v - __bfloat162float(hi);
    size_t o = (size_t)(n0 + r) * K + k0 + c;
    ohi[o] = hi;
    olo[o] = __float2bfloat16(lo);
  }
}

// ------- pack x: [4][64][4096][2] f32 -> XP[16384][128] bf16 hi/lo ---------
__global__ __launch_bounds__(256) void k_packx(const float* __restrict__ x,
                                               bf16* __restrict__ XPhi,
                                               bf16* __restrict__ XPlo) {
  int idx = blockIdx.x * 256 + threadIdx.x;  // 2,097,152 total
  int k = idx & 127, row = idx >> 7;
  int b = row >> 12, n = row & 4095;
  int tt = k >> 1, c = k & 1;
  float v = x[(((size_t)(b * 64 + tt)) * SEQ + n) * 2 + c];
  bf16 hi = __float2bfloat16(v);
  XPhi[idx] = hi;
  XPlo[idx] = __float2bfloat16(v - __bfloat162float(hi));
}

// ------- LayerNorm: H f32 [HTOK][512] -> Y bf16 hi/lo ----------------------
__global__ __launch_bounds__(256) void k_ln(const float* __restrict__ H,
                                            const float* __restrict__ G,
                                            const float* __restrict__ B,
                                            bf16* __restrict__ Yhi,
                                            bf16* __restrict__ Ylo) {
  int t = threadIdx.x, lane = t & 63;
  int row = blockIdx.x * 4 + (t >> 6);
  const float4* h4 = (const float4*)(H + (size_t)row * HID);
  float4 a = h4[lane * 2], b = h4[lane * 2 + 1];
  float v[8] = {a.x, a.y, a.z, a.w, b.x, b.y, b.z, b.w};
  float s = v[0] + v[1] + v[2] + v[3] + v[4] + v[5] + v[6] + v[7];
  s = wred(s);
  float m = s * (1.0f / 512.0f);
  float q = 0.f;
#pragma unroll
  for (int i = 0; i < 8; ++i) {
    v[i] -= m;
    q += v[i] * v[i];
  }
  q = wred(q);
  float rs = rsqrtf(q * (1.0f / 512.0f) + 1e-5f);
  const float4* g4 = (const float4*)G;
  const float4* b4 = (const float4*)B;
  float4 g1 = g4[lane * 2], g2 = g4[lane * 2 + 1];
  float4 e1 = b4[lane * 2], e2 = b4[lane * 2 + 1];
  float gg[8] = {g1.x, g1.y, g1.z, g1.w, g2.x, g2.y, g2.z, g2.w};
  float ee[8] = {e1.x, e1.y, e1.z, e1.w, e2.x, e2.y, e2.z, e2.w};
  union { u16x8 v; unsigned short s_[8]; } uh, ul;
#pragma unroll
  for (int i = 0; i < 8; ++i) {
    float y = v[i] * rs * gg[i] + ee[i];
    unsigned short hb = f2b(y);
    uh.s_[i] = hb;
    ul.s_[i] = f2b(y - b2f(hb));
  }
  *reinterpret_cast<u16x8*>((unsigned short*)Yhi + (size_t)row * HID + lane * 8) = uh.v;
  *reinterpret_cast<u16x8*>((unsigned short*)Ylo + (size_t)row * HID + lane * 8) = ul.v;
}

// ------- dots partials: DOTSP[chunk][bh16][64*64], f32 (k,v = hi+lo) -------
// Half-batch: QKV has 8192 rows (2 local batches); bh = blockIdx.y in 0..15.
__global__ __launch_bounds__(256) void k_dots(const bf16* __restrict__ Qhi,
                                              const bf16* __restrict__ Qlo,
                                              float* __restrict__ DOTSP) {
  int bh = blockIdx.y, b = bh >> 3, h = bh & 7;
  int n0 = blockIdx.x * 512;
  __shared__ alignas(16) short khi[64 * 64];
  __shared__ alignas(16) short klo[64 * 64];
  __shared__ alignas(16) short vhi[64 * 64];
  __shared__ alignas(16) short vlo[64 * 64];
  int t = threadIdx.x;
  int d0 = (t & 15) * 4, e0 = (t >> 4) * 4;
  float acc[4][4] = {};
  for (int sub = 0; sub < 8; ++sub) {
    int nb = n0 + sub * 64;
#pragma unroll
    for (int i = 0; i < 2; ++i) {
      int c = t + i * 256;
      int r = c >> 3, off = (c & 7) << 3;
      size_t rowoff = (size_t)(b * SEQ + nb + r) * 1536;
      const short* ph = (const short*)Qhi + rowoff;
      const short* pl = (const short*)Qlo + rowoff;
      gload16(ph + 512 + h * 64 + off, khi + c * 8);
      gload16(pl + 512 + h * 64 + off, klo + c * 8);
      gload16(ph + 1024 + h * 64 + off, vhi + c * 8);
      gload16(pl + 1024 + h * 64 + off, vlo + c * 8);
    }
    asm volatile("s_waitcnt vmcnt(0)" ::: "memory");
    __syncthreads();
    for (int r = 0; r < 64; ++r) {
      short4 ka = *(const short4*)&khi[r * 64 + d0];
      short4 kb = *(const short4*)&klo[r * 64 + d0];
      short4 va = *(const short4*)&vhi[r * 64 + e0];
      short4 vb = *(const short4*)&vlo[r * 64 + e0];
      float kf[4] = {b2f((unsigned short)ka.x) + b2f((unsigned short)kb.x),
                     b2f((unsigned short)ka.y) + b2f((unsigned short)kb.y),
                     b2f((unsigned short)ka.z) + b2f((unsigned short)kb.z),
                     b2f((unsigned short)ka.w) + b2f((unsigned short)kb.w)};
      float vf[4] = {b2f((unsigned short)va.x) + b2f((unsigned short)vb.x),
                     b2f((unsigned short)va.y) + b2f((unsigned short)vb.y),
                     b2f((unsigned short)va.z) + b2f((unsigned short)vb.z),
                     b2f((unsigned short)va.w) + b2f((unsigned short)vb.w)};
#pragma unroll
      for (int i = 0; i < 4; ++i)
#pragma unroll
        for (int j = 0; j < 4; ++j) acc[i][j] += kf[i] * vf[j];
    }
    __syncthreads();
  }
  float* dst = DOTSP + ((size_t)blockIdx.x * 16 + bh) * 4096;
#pragma unroll
  for (int i = 0; i < 4; ++i)
#pragma unroll
    for (int j = 0; j < 4; ++j) dst[(d0 + i) * 64 + e0 + j] = acc[i][j];
}

__global__ __launch_bounds__(256) void k_reddots(const float* __restrict__ P,
                                                 float* __restrict__ D) {
  int i = blockIdx.x * 256 + threadIdx.x;  // 65536
  float s = 0.f;
#pragma unroll
  for (int c = 0; c < 8; ++c) s += P[(size_t)c * 65536 + i];
  D[i] = s;
}

// ------- o = q @ dots * (1/n) -> O bf16 hi/lo [HTOK][512] ------------------
__global__ __launch_bounds__(256) void k_ov(const bf16* __restrict__ Qhi,
                                            const bf16* __restrict__ Qlo,
                                            const float* __restrict__ DOTS,
                                            bf16* __restrict__ Ohi,
                                            bf16* __restrict__ Olo) {
  int bh = blockIdx.y, b = bh >> 3, h = bh & 7;
  int n0 = blockIdx.x * 64;
  __shared__ alignas(16) float ds[64 * 64];
  __shared__ alignas(16) short qhi[64 * 64];
  __shared__ alignas(16) short qlo[64 * 64];
  int t = threadIdx.x;
  const float* dsrc = DOTS + (size_t)bh * 4096;
#pragma unroll
  for (int i = 0; i < 16; ++i) ds[t + i * 256] = dsrc[t + i * 256];
#pragma unroll
  for (int i = 0; i < 2; ++i) {
    int c = t + i * 256, r = c >> 3, off = (c & 7) << 3;
    size_t rowoff = (size_t)(b * SEQ + n0 + r) * 1536;
    gload16((const short*)Qhi + rowoff + h * 64 + off, qhi + c * 8);
    gload16((const short*)Qlo + rowoff + h * 64 + off, qlo + c * 8);
  }
  asm volatile("s_waitcnt vmcnt(0)" ::: "memory");
  __syncthreads();
  int wv = t >> 6, lane = t & 63;
  for (int tok = wv; tok < 64; tok += 4) {
    float acc = 0.f;
#pragma unroll
    for (int d = 0; d < 64; d += 4) {
      short4 qa = *(const short4*)&qhi[tok * 64 + d];
      short4 qb = *(const short4*)&qlo[tok * 64 + d];
      acc += (b2f((unsigned short)qa.x) + b2f((unsigned short)qb.x)) * ds[(d + 0) * 64 + lane];
      acc += (b2f((unsigned short)qa.y) + b2f((unsigned short)qb.y)) * ds[(d + 1) * 64 + lane];
      acc += (b2f((unsigned short)qa.z) + b2f((unsigned short)qb.z)) * ds[(d + 2) * 64 + lane];
      acc += (b2f((unsigned short)qa.w) + b2f((unsigned short)qb.w)) * ds[(d + 3) * 64 + lane];
    }
    float res = acc * (1.0f / SEQ);
    bf16 hi = __float2bfloat16(res);
    size_t o = (size_t)(b * SEQ + n0 + tok) * 512 + h * 64 + lane;
    Ohi[o] = hi;
    Olo[o] = __float2bfloat16(res - __bfloat162float(hi));
  }
}

// ------- split-split MFMA GEMM: 4 tiles [Ahi,Alo,B1,B2], 128x128, BK=32 ----
// Non-gated: B1=Bhi, B2=Blo -> acc = ah*bh + al*bh + ah*bl
// Gated (MODE 5): B1=W1 value-half, B2=W1 gate-half (single bf16 each)
// MODE 0: out32 = (acc + bias)*sqrt(512) + posenc      (embed -> H)
// MODE 1: fused inorm on k/v cols; o16a/b = QKV hi/lo  (qkv)
// MODE 2: H = acc + bias + Hin; o16a/b = hi/lo         (Wout / W2 + residual)
// MODE 5: gated: f = gelu(acc+b)*(acc2+b2) -> hi/lo    (W1 -> F)
// MODE 7: out32[b, col*4096+n] = acc + bias            (final, transposed)
__device__ __forceinline__ void stage_t(const bf16* g, int ldk, int rowBase,
                                        int k0, short* lds, int t) {
  const short* gs = (const short*)g;
#pragma unroll
  for (int i = 0; i < 2; ++i) {
    int c = t + i * 256;
    int r = c >> 2, ko = (c & 3) << 3;
    gload16(gs + (size_t)(rowBase + r) * ldk + k0 + ko, lds + c * 8);
  }
}

template <int MODE>
__global__ __launch_bounds__(256, (MODE == 5) ? 1 : 2) void k_gemm(
    const bf16* __restrict__ Ahi, const bf16* __restrict__ Alo,
    const bf16* __restrict__ B1, const bf16* __restrict__ B2, int K,
    const float* __restrict__ bias, const float* __restrict__ Hin,
    float* __restrict__ out32, bf16* __restrict__ o16a,
    bf16* __restrict__ o16b, int ldo) {
  constexpr bool GATED = (MODE == 5);
  __shared__ alignas(16) short sm[2][4][128 * 32];
  const int t = threadIdx.x, lane = t & 63;
  const int wv = t >> 6, wr = wv >> 1, wc = wv & 1;
  const int r16 = lane & 15, grp = lane >> 4;
  const int mBase = blockIdx.y * 128, nBase = blockIdx.x * 128;
  const int NT = K >> 5;

  f32x4 acc[4][4] = {};
  f32x4 acc2[GATED ? 4 : 1][GATED ? 4 : 1] = {};

  auto stage_all = [&](int sb, int k0) {
    stage_t(Ahi, K, mBase, k0, &sm[sb][0][0], t);
    stage_t(Alo, K, mBase, k0, &sm[sb][1][0], t);
    stage_t(B1, K, nBase, k0, &sm[sb][2][0], t);
    stage_t(B2, K, nBase, k0, &sm[sb][3][0], t);
  };

  stage_all(0, 0);
  asm volatile("s_waitcnt vmcnt(0)" ::: "memory");
  __syncthreads();

  int buf = 0;
  for (int kt = 0; kt < NT; ++kt) {
    if (kt + 1 < NT) stage_all(buf ^ 1, (kt + 1) << 5);
    const int fo = grp * 8;
    bf16x8 ah[4], al[4], b1v[4], b2v[4];
#pragma unroll
    for (int f = 0; f < 4; ++f) {
      int ro = (wr * 64 + f * 16 + r16) * 32 + fo;
      ah[f] = *(const bf16x8*)&sm[buf][0][ro];
      al[f] = *(const bf16x8*)&sm[buf][1][ro];
    }
#pragma unroll
    for (int f = 0; f < 4; ++f) {
      int co = (wc * 64 + f * 16 + r16) * 32 + fo;
      b1v[f] = *(const bf16x8*)&sm[buf][2][co];
      b2v[f] = *(const bf16x8*)&sm[buf][3][co];
    }
    if constexpr (!GATED) {
#pragma unroll
      for (int i = 0; i < 4; ++i)
#pragma unroll
        for (int j = 0; j < 4; ++j) {
          acc[i][j] = __builtin_amdgcn_mfma_f32_16x16x32_bf16(ah[i], b1v[j], acc[i][j], 0, 0, 0);
          acc[i][j] = __builtin_amdgcn_mfma_f32_16x16x32_bf16(al[i], b1v[j], acc[i][j], 0, 0, 0);
          acc[i][j] = __builtin_amdgcn_mfma_f32_16x16x32_bf16(ah[i], b2v[j], acc[i][j], 0, 0, 0);
        }
    } else {
#pragma unroll
      for (int i = 0; i < 4; ++i)
#pragma unroll
        for (int j = 0; j < 4; ++j) {
          acc[i][j] = __builtin_amdgcn_mfma_f32_16x16x32_bf16(ah[i], b1v[j], acc[i][j], 0, 0, 0);
          acc[i][j] = __builtin_amdgcn_mfma_f32_16x16x32_bf16(al[i], b1v[j], acc[i][j], 0, 0, 0);
          acc2[i][j] = __builtin_amdgcn_mfma_f32_16x16x32_bf16(ah[i], b2v[j], acc2[i][j], 0, 0, 0);
          acc2[i][j] = __builtin_amdgcn_mfma_f32_16x16x32_bf16(al[i], b2v[j], acc2[i][j], 0, 0, 0);
        }
    }
    if (kt + 1 < NT) {
      asm volatile("s_waitcnt vmcnt(0)" ::: "memory");
      __syncthreads();
      buf ^= 1;
    }
  }

  if constexpr (MODE == 1) {
    // fused InstanceNorm over each 64-col head group (k/v thirds only)
    const bool doNorm = (nBase >= 512);
#pragma unroll
    for (int i = 0; i < 4; ++i) {
#pragma unroll
      for (int r = 0; r < 4; ++r) {
        float s = 0.f, s2 = 0.f;
#pragma unroll
        for (int j = 0; j < 4; ++j) {
          float v = acc[i][j][r];
          s += v;
          s2 += v * v;
        }
#pragma unroll
        for (int off = 8; off; off >>= 1) {
          s += __shfl_xor(s, off);
          s2 += __shfl_xor(s2, off);
        }
        float m = s * (1.0f / 64.0f);
        float var = fmaxf(s2 * (1.0f / 64.0f) - m * m, 0.f);
        float rs = rsqrtf(var + 1e-5f);
        int row = mBase + wr * 64 + i * 16 + grp * 4 + r;
#pragma unroll
        for (int j = 0; j < 4; ++j) {
          int col = nBase + wc * 64 + j * 16 + r16;
          float v = acc[i][j][r];
          if (doNorm) v = (v - m) * rs;
          bf16 hi = __float2bfloat16(v);
          float lo = v - __bfloat162float(hi);
          size_t o = (size_t)row * ldo + col;
          o16a[o] = hi;
          o16b[o] = __float2bfloat16(lo);
        }
      }
    }
    return;
  }

#pragma unroll
  for (int i = 0; i < 4; ++i) {
#pragma unroll
    for (int j = 0; j < 4; ++j) {
#pragma unroll
      for (int r = 0; r < 4; ++r) {
        int row = mBase + wr * 64 + i * 16 + grp * 4 + r;
        int col = nBase + wc * 64 + j * 16 + r16;
        float v = acc[i][j][r];
        if constexpr (MODE == 0) {
          v = (v + bias[col]) * 22.627416997969522f;
          int n = row & (SEQ - 1);
          int k2 = col >> 1;
          float ang = (float)n * expf((float)k2 * -0.03597789207803197f);
          v += (col & 1) ? cosf(ang) : sinf(ang);
          out32[(size_t)row * HID + col] = v;
        } else if constexpr (MODE == 2) {
          v += bias[col] + Hin[(size_t)row * HID + col];
          out32[(size_t)row * HID + col] = v;
          bf16 hi = __float2bfloat16(v);
          float lo = v - __bfloat162float(hi);
          o16a[(size_t)row * HID + col] = hi;
          o16b[(size_t)row * HID + col] = __float2bfloat16(lo);
        } else if constexpr (MODE == 7) {
          v += bias[col];
          out32[(size_t)(row >> 12) * (128 * 4096) + (size_t)col * SEQ + (row & 4095)] = v;
        } else {  // MODE 5: gated
          float a = v + bias[col];
          float c2 = acc2[i][j][r] + bias[2048 + col];
          float gl = 0.5f * a * (1.0f + erff(a * 0.7071067811865475f));
          float f = gl * c2;
          bf16 hi = __float2bfloat16(f);
          float lo = f - __bfloat162float(hi);
          o16a[(size_t)row * ldo + col] = hi;
          o16b[(size_t)row * ldo + col] = __float2bfloat16(lo);
        }
      }
    }
  }
}

// ---------------------------------------------------------------------------
extern "C" void kernel_launch(void* const* d_in, const int* in_sizes, int n_in,
                              void* d_out, int out_size, void* d_ws, size_t ws_size,
                              hipStream_t stream) {
  const float* x    = (const float*)d_in[0];
  const float* Wemb = (const float*)d_in[1];
  const float* bemb = (const float*)d_in[2];
  const float* lng  = (const float*)d_in[3];
  const float* lnb  = (const float*)d_in[4];
  const float* Wqkv = (const float*)d_in[5];
  const float* Wout = (const float*)d_in[6];
  const float* bout = (const float*)d_in[7];
  const float* W1   = (const float*)d_in[8];
  const float* b1   = (const float*)d_in[9];
  const float* W2   = (const float*)d_in[10];
  const float* b2   = (const float*)d_in[11];
  const float* Wd   = (const float*)d_in[12];
  const float* bd   = (const float*)d_in[13];

  char* p = (char*)d_ws;
  auto alloc = [&](size_t bytes) {
    char* r = p;
    p += (bytes + 255) & ~(size_t)255;
    return r;
  };
  // ---- total budget ~213 MB (ws_size is ~256MiB) ----
  bf16* WembH = (bf16*)alloc((size_t)512 * 128 * 2);
  bf16* WembL = (bf16*)alloc((size_t)512 * 128 * 2);
  bf16* WqkvH = (bf16*)alloc((size_t)6 * 1536 * 512 * 2);
  bf16* WqkvL = (bf16*)alloc((size_t)6 * 1536 * 512 * 2);
  bf16* WoutH = (bf16*)alloc((size_t)6 * 512 * 512 * 2);
  bf16* WoutL = (bf16*)alloc((size_t)6 * 512 * 512 * 2);
  bf16* W1H   = (bf16*)alloc((size_t)6 * 4096 * 512 * 2);   // no W1L (gated B single)
  bf16* W2H   = (bf16*)alloc((size_t)6 * 512 * 2048 * 2);
  bf16* W2L   = (bf16*)alloc((size_t)6 * 512 * 2048 * 2);
  bf16* WdH   = (bf16*)alloc((size_t)128 * 512 * 2);
  bf16* WdL   = (bf16*)alloc((size_t)128 * 512 * 2);
  float* H    = (float*)alloc((size_t)NTOK * 512 * 4);      // 32MB residual
  bf16* HBhi  = (bf16*)alloc((size_t)NTOK * 512 * 2);
  bf16* HBlo  = (bf16*)alloc((size_t)NTOK * 512 * 2);
  float* DOTSP = (float*)alloc((size_t)8 * 16 * 4096 * 4);  // 2MB
  float* DOTS  = (float*)alloc((size_t)16 * 4096 * 4);      // 256KB
  // Union region U (64 MiB), per-HALF lifetimes:
  //  pre-loop: XPhi@0, XPlo@4Mi, W1-lo-scratch@8Mi (dead after transposes)
  //  attn:  Yhi@0(8M) Ylo@8Mi(8M) QKVhi@16Mi(24M) QKVlo@40Mi(24M)
  //  ov:    Ohi@0 Olo@8Mi (Y dead)
  //  mlp:   Fhi@0(32M) Flo@32Mi(32M) (QKV,O dead)
  char* U = alloc((size_t)64 * 1024 * 1024);
  const size_t MI = 1024 * 1024;
  bf16* XPhi  = (bf16*)U;
  bf16* XPlo  = (bf16*)(U + 4 * MI);
  bf16* W1scr = (bf16*)(U + 8 * MI);
  bf16* Yhi   = (bf16*)U;
  bf16* Ylo   = (bf16*)(U + 8 * MI);
  bf16* QKVhi = (bf16*)(U + 16 * MI);
  bf16* QKVlo = (bf16*)(U + 40 * MI);
  bf16* Ohi   = (bf16*)U;
  bf16* Olo   = (bf16*)(U + 8 * MI);
  bf16* Fhi   = (bf16*)U;
  bf16* Flo   = (bf16*)(U + 32 * MI);

  // weights -> bf16 hi/lo, transposed to [N][K]
  k_transpose<<<dim3(2, 8, 1),  256, 0, stream>>>(Wemb, WembH, WembL, 128, 512);
  k_transpose<<<dim3(8, 24, 6), 256, 0, stream>>>(Wqkv, WqkvH, WqkvL, 512, 1536);
  k_transpose<<<dim3(8, 8, 6),  256, 0, stream>>>(Wout, WoutH, WoutL, 512, 512);
  k_transpose<<<dim3(8, 64, 6), 256, 0, stream>>>(W1, W1H, W1scr, 512, 4096);
  k_transpose<<<dim3(32, 8, 6), 256, 0, stream>>>(W2, W2H, W2L, 2048, 512);
  k_transpose<<<dim3(8, 2, 1),  256, 0, stream>>>(Wd, WdH, WdL, 512, 128);

  k_packx<<<8192, 256, 0, stream>>>(x, XPhi, XPlo);
  // embed: H = (XP @ Wemb + b)*sqrt(512) + posenc   (full 16384 rows)
  k_gemm<0><<<dim3(4, 128), 256, 0, stream>>>(XPhi, XPlo, WembH, WembL, 128,
      bemb, nullptr, H, nullptr, nullptr, 0);

  for (int i = 0; i < 6; ++i) {
    for (int hb = 0; hb < 2; ++hb) {
      const size_t R0 = (size_t)hb * HTOK;
      k_ln<<<2048, 256, 0, stream>>>(H + R0 * 512, lng + i * 512, lnb + i * 512,
                                     Yhi, Ylo);
      k_gemm<1><<<dim3(12, 64), 256, 0, stream>>>(Yhi, Ylo,
          WqkvH + (size_t)i * 1536 * 512, WqkvL + (size_t)i * 1536 * 512, 512,
          nullptr, nullptr, nullptr, QKVhi, QKVlo, 1536);
      k_dots<<<dim3(8, 16), 256, 0, stream>>>(QKVhi, QKVlo, DOTSP);
      k_reddots<<<256, 256, 0, stream>>>(DOTSP, DOTS);
      k_ov<<<dim3(64, 16), 256, 0, stream>>>(QKVhi, QKVlo, DOTS, Ohi, Olo);
      k_gemm<2><<<dim3(4, 64), 256, 0, stream>>>(Ohi, Olo,
          WoutH + (size_t)i * 512 * 512, WoutL + (size_t)i * 512 * 512, 512,
          bout + i * 512, H + R0 * 512, H + R0 * 512,
          HBhi + R0 * 512, HBlo + R0 * 512, 512);
      k_gemm<5><<<dim3(16, 64), 256, 0, stream>>>(HBhi + R0 * 512, HBlo + R0 * 512,
          W1H + (size_t)i * 4096 * 512,
          W1H + (size_t)i * 4096 * 512 + (size_t)2048 * 512, 512,
          b1 + i * 4096, nullptr, nullptr, Fhi, Flo, 2048);
      k_gemm<2><<<dim3(4, 64), 256, 0, stream>>>(Fhi, Flo,
          W2H + (size_t)i * 512 * 2048, W2L + (size_t)i * 512 * 2048, 2048,
          b2 + i * 512, H + R0 * 512, H + R0 * 512,
          HBhi + R0 * 512, HBlo + R0 * 512, 512);
    }
  }
  // final: out[b, col*4096+n] = h @ Wd + bd   (full rows)
  k_gemm<7><<<dim3(1, 128), 256, 0, stream>>>(HBhi, HBlo, WdH, WdL, 512, bd,
      nullptr, (float*)d_out, nullptr, nullptr, 0);
}

// Round 7
// 1910.739 us; speedup vs baseline: 2.3656x; 2.3656x over previous
//
#include <hip/hip_runtime.h>
#include <hip/hip_bf16.h>
#include <stdint.h>
#include <math.h>

// POD_GalerkinTransformer forward, MI355X (gfx950).
// Single-fp16 MFMA GEMMs (16x16x32_f16, one MFMA per acc), 128x128 tile,
// BK=32, double-buffered LDS via global_load_lds. fp16 rounding (11-bit
// mantissa) keeps total error ~8x below the bf16 baseline (R1: 2.48%).
// Large-magnitude A operands (h, f) carried as fp16 * 1/256 (exact pow2,
// unscaled in epilogue). Residual h f32; attention math f32 from fp16;
// InstanceNorm fused into qkv epilogue. Workspace ~167MB (limit ~256MiB).

typedef _Float16 f16x8 __attribute__((ext_vector_type(8)));
typedef float f32x4 __attribute__((ext_vector_type(4)));
typedef unsigned short u16x8 __attribute__((ext_vector_type(8)));
typedef unsigned short u16;

#define SEQ 4096
#define NTOK 16384
#define HID 512
#define RSCL 256.0f        // h,f stored as fp16*(1/RSCL)
#define RSCLI (1.0f/256.0f)

__device__ __forceinline__ float wred(float x) {
#pragma unroll
  for (int off = 32; off; off >>= 1) x += __shfl_xor(x, off);
  return x;
}

__device__ __forceinline__ u16 f2h(float v) {
  _Float16 h = (_Float16)v;
  return __builtin_bit_cast(u16, h);
}
__device__ __forceinline__ float h2f(u16 u) {
  return (float)__builtin_bit_cast(_Float16, u);
}

__device__ __forceinline__ void gload16(const void* g, void* l) {
  __builtin_amdgcn_global_load_lds(
      reinterpret_cast<const __attribute__((address_space(1))) int*>(
          reinterpret_cast<uintptr_t>(g)),
      reinterpret_cast<__attribute__((address_space(3))) int*>(
          reinterpret_cast<uintptr_t>(l)),
      16, 0, 0);
}

// ------- weight transpose+cast: [D][K][N] f32 -> [D][N][K] fp16 ------------
__global__ __launch_bounds__(256) void k_transpose(const float* __restrict__ src,
                                                   u16* __restrict__ dst,
                                                   int K, int N) {
  int d = blockIdx.z;
  const float* s = src + (size_t)d * K * N;
  u16* o = dst + (size_t)d * N * K;
  int k0 = blockIdx.x * 64, n0 = blockIdx.y * 64;
  __shared__ float tile[64][65];
  int t = threadIdx.x, c = t & 63, r4 = t >> 6;
#pragma unroll
  for (int i = 0; i < 16; ++i) {
    int r = i * 4 + r4;
    tile[r][c] = s[(size_t)(k0 + r) * N + n0 + c];
  }
  __syncthreads();
#pragma unroll
  for (int i = 0; i < 16; ++i) {
    int r = i * 4 + r4;
    o[(size_t)(n0 + r) * K + k0 + c] = f2h(tile[c][r]);
  }
}

// ------- pack x: [4][64][4096][2] f32 -> XP[16384][128] fp16 ---------------
__global__ __launch_bounds__(256) void k_packx(const float* __restrict__ x,
                                               u16* __restrict__ XP) {
  int idx = blockIdx.x * 256 + threadIdx.x;  // 2,097,152 total
  int k = idx & 127, row = idx >> 7;
  int b = row >> 12, n = row & 4095;
  int tt = k >> 1, c = k & 1;
  XP[idx] = f2h(x[(((size_t)(b * 64 + tt)) * SEQ + n) * 2 + c]);
}

// ------- LayerNorm: H f32 [NTOK][512] -> Y fp16 ----------------------------
__global__ __launch_bounds__(256) void k_ln(const float* __restrict__ H,
                                            const float* __restrict__ G,
                                            const float* __restrict__ B,
                                            u16* __restrict__ Y) {
  int t = threadIdx.x, lane = t & 63;
  int row = blockIdx.x * 4 + (t >> 6);
  const float4* h4 = (const float4*)(H + (size_t)row * HID);
  float4 a = h4[lane * 2], b = h4[lane * 2 + 1];
  float v[8] = {a.x, a.y, a.z, a.w, b.x, b.y, b.z, b.w};
  float s = v[0] + v[1] + v[2] + v[3] + v[4] + v[5] + v[6] + v[7];
  s = wred(s);
  float m = s * (1.0f / 512.0f);
  float q = 0.f;
#pragma unroll
  for (int i = 0; i < 8; ++i) {
    v[i] -= m;
    q += v[i] * v[i];
  }
  q = wred(q);
  float rs = rsqrtf(q * (1.0f / 512.0f) + 1e-5f);
  const float4* g4 = (const float4*)G;
  const float4* b4 = (const float4*)B;
  float4 g1 = g4[lane * 2], g2 = g4[lane * 2 + 1];
  float4 e1 = b4[lane * 2], e2 = b4[lane * 2 + 1];
  float gg[8] = {g1.x, g1.y, g1.z, g1.w, g2.x, g2.y, g2.z, g2.w};
  float ee[8] = {e1.x, e1.y, e1.z, e1.w, e2.x, e2.y, e2.z, e2.w};
  union { u16x8 v; u16 s_[8]; } uh;
#pragma unroll
  for (int i = 0; i < 8; ++i) uh.s_[i] = f2h(v[i] * rs * gg[i] + ee[i]);
  *reinterpret_cast<u16x8*>((u16*)Y + (size_t)row * HID + lane * 8) = uh.v;
}

// ------- dots partials: DOTSP[chunk][bh32][64*64], f32 from fp16 -----------
__global__ __launch_bounds__(256) void k_dots(const u16* __restrict__ QKV,
                                              float* __restrict__ DOTSP) {
  int bh = blockIdx.y, b = bh >> 3, h = bh & 7;
  int n0 = blockIdx.x * 512;
  __shared__ alignas(16) short ks[64 * 64];
  __shared__ alignas(16) short vs[64 * 64];
  int t = threadIdx.x;
  int d0 = (t & 15) * 4, e0 = (t >> 4) * 4;
  float acc[4][4] = {};
  for (int sub = 0; sub < 8; ++sub) {
    int nb = n0 + sub * 64;
#pragma unroll
    for (int i = 0; i < 2; ++i) {
      int c = t + i * 256;
      int r = c >> 3, off = (c & 7) << 3;
      const u16* base = QKV + (size_t)(b * SEQ + nb + r) * 1536;
      gload16(base + 512 + h * 64 + off, ks + c * 8);
      gload16(base + 1024 + h * 64 + off, vs + c * 8);
    }
    asm volatile("s_waitcnt vmcnt(0)" ::: "memory");
    __syncthreads();
    for (int r = 0; r < 64; ++r) {
      short4 kk = *(const short4*)&ks[r * 64 + d0];
      short4 vv = *(const short4*)&vs[r * 64 + e0];
      float kf[4] = {h2f((u16)kk.x), h2f((u16)kk.y), h2f((u16)kk.z), h2f((u16)kk.w)};
      float vf[4] = {h2f((u16)vv.x), h2f((u16)vv.y), h2f((u16)vv.z), h2f((u16)vv.w)};
#pragma unroll
      for (int i = 0; i < 4; ++i)
#pragma unroll
        for (int j = 0; j < 4; ++j) acc[i][j] += kf[i] * vf[j];
    }
    __syncthreads();
  }
  float* dst = DOTSP + ((size_t)blockIdx.x * 32 + bh) * 4096;
#pragma unroll
  for (int i = 0; i < 4; ++i)
#pragma unroll
    for (int j = 0; j < 4; ++j) dst[(d0 + i) * 64 + e0 + j] = acc[i][j];
}

__global__ __launch_bounds__(256) void k_reddots(const float* __restrict__ P,
                                                 float* __restrict__ D) {
  int i = blockIdx.x * 256 + threadIdx.x;  // 131072
  float s = 0.f;
#pragma unroll
  for (int c = 0; c < 8; ++c) s += P[(size_t)c * 131072 + i];
  D[i] = s;
}

// ------- o = q @ dots * (1/n) -> O fp16 [NTOK][512] ------------------------
__global__ __launch_bounds__(256) void k_ov(const u16* __restrict__ QKV,
                                            const float* __restrict__ DOTS,
                                            u16* __restrict__ O) {
  int bh = blockIdx.y, b = bh >> 3, h = bh & 7;
  int n0 = blockIdx.x * 64;
  __shared__ alignas(16) float ds[64 * 64];
  __shared__ alignas(16) short qs[64 * 64];
  int t = threadIdx.x;
  const float* dsrc = DOTS + (size_t)bh * 4096;
#pragma unroll
  for (int i = 0; i < 16; ++i) ds[t + i * 256] = dsrc[t + i * 256];
#pragma unroll
  for (int i = 0; i < 2; ++i) {
    int c = t + i * 256, r = c >> 3, off = (c & 7) << 3;
    gload16(QKV + (size_t)(b * SEQ + n0 + r) * 1536 + h * 64 + off, qs + c * 8);
  }
  asm volatile("s_waitcnt vmcnt(0)" ::: "memory");
  __syncthreads();
  int wv = t >> 6, lane = t & 63;
  for (int tok = wv; tok < 64; tok += 4) {
    float acc = 0.f;
#pragma unroll
    for (int d = 0; d < 64; d += 4) {
      short4 q4 = *(const short4*)&qs[tok * 64 + d];
      acc += h2f((u16)q4.x) * ds[(d + 0) * 64 + lane];
      acc += h2f((u16)q4.y) * ds[(d + 1) * 64 + lane];
      acc += h2f((u16)q4.z) * ds[(d + 2) * 64 + lane];
      acc += h2f((u16)q4.w) * ds[(d + 3) * 64 + lane];
    }
    O[(size_t)(b * SEQ + n0 + tok) * 512 + h * 64 + lane] = f2h(acc * (1.0f / SEQ));
  }
}

// ------- fp16 MFMA GEMM: 128x128 tile, BK=32, double-buffered --------------
// MODE 0: H = (acc + bias)*sqrt(512) + posenc             (embed)
// MODE 1: fused inorm on k/v head groups; QKV fp16 = o16  (qkv)
// MODE 2: H = acc*ascale + bias + Hin; o16 = fp16(H/256)  (Wout ascale=1 / W2 ascale=256)
// MODE 5: gated: f = gelu(256*acc+b)*(256*acc2+b2); o16 = fp16(f/256)  (W1)
// MODE 7: out32[b, col*4096+n] = 256*acc + bias           (final, transposed)
__device__ __forceinline__ void stage_t(const u16* g, int ldk, int rowBase,
                                        int k0, short* lds, int t) {
#pragma unroll
  for (int i = 0; i < 2; ++i) {
    int c = t + i * 256;
    int r = c >> 2, ko = (c & 3) << 3;
    gload16(g + (size_t)(rowBase + r) * ldk + k0 + ko, lds + c * 8);
  }
}

template <int MODE>
__global__ __launch_bounds__(256, 2) void k_gemm(
    const u16* __restrict__ A, const u16* __restrict__ B1,
    const u16* __restrict__ B2, int K,
    const float* __restrict__ bias, const float* __restrict__ Hin,
    float ascale, float* __restrict__ out32, u16* __restrict__ o16, int ldo) {
  constexpr bool GATED = (MODE == 5);
  constexpr int NTILE = GATED ? 3 : 2;
  __shared__ alignas(16) short sm[2][NTILE][128 * 32];
  const int t = threadIdx.x, lane = t & 63;
  const int wv = t >> 6, wr = wv >> 1, wc = wv & 1;
  const int r16 = lane & 15, grp = lane >> 4;
  const int mBase = blockIdx.y * 128, nBase = blockIdx.x * 128;
  const int NT = K >> 5;

  f32x4 acc[4][4] = {};
  f32x4 acc2[GATED ? 4 : 1][GATED ? 4 : 1] = {};

  auto stage_all = [&](int sb, int k0) {
    stage_t(A, K, mBase, k0, &sm[sb][0][0], t);
    stage_t(B1, K, nBase, k0, &sm[sb][1][0], t);
    if constexpr (GATED) stage_t(B2, K, nBase, k0, &sm[sb][2][0], t);
  };

  stage_all(0, 0);
  asm volatile("s_waitcnt vmcnt(0)" ::: "memory");
  __syncthreads();

  int buf = 0;
  for (int kt = 0; kt < NT; ++kt) {
    if (kt + 1 < NT) stage_all(buf ^ 1, (kt + 1) << 5);
    const int fo = grp * 8;
    f16x8 af[4], b1v[4];
#pragma unroll
    for (int f = 0; f < 4; ++f)
      af[f] = *(const f16x8*)&sm[buf][0][(wr * 64 + f * 16 + r16) * 32 + fo];
#pragma unroll
    for (int f = 0; f < 4; ++f)
      b1v[f] = *(const f16x8*)&sm[buf][1][(wc * 64 + f * 16 + r16) * 32 + fo];
#pragma unroll
    for (int i = 0; i < 4; ++i)
#pragma unroll
      for (int j = 0; j < 4; ++j)
        acc[i][j] = __builtin_amdgcn_mfma_f32_16x16x32_f16(af[i], b1v[j], acc[i][j], 0, 0, 0);
    if constexpr (GATED) {
      f16x8 b2v[4];
#pragma unroll
      for (int f = 0; f < 4; ++f)
        b2v[f] = *(const f16x8*)&sm[buf][2][(wc * 64 + f * 16 + r16) * 32 + fo];
#pragma unroll
      for (int i = 0; i < 4; ++i)
#pragma unroll
        for (int j = 0; j < 4; ++j)
          acc2[i][j] = __builtin_amdgcn_mfma_f32_16x16x32_f16(af[i], b2v[j], acc2[i][j], 0, 0, 0);
    }
    if (kt + 1 < NT) {
      asm volatile("s_waitcnt vmcnt(0)" ::: "memory");
      __syncthreads();
      buf ^= 1;
    }
  }

  if constexpr (MODE == 1) {
    // fused InstanceNorm over each 64-col head group (k/v thirds only)
    const bool doNorm = (nBase >= 512);
#pragma unroll
    for (int i = 0; i < 4; ++i) {
#pragma unroll
      for (int r = 0; r < 4; ++r) {
        float s = 0.f, s2 = 0.f;
#pragma unroll
        for (int j = 0; j < 4; ++j) {
          float v = acc[i][j][r];
          s += v;
          s2 += v * v;
        }
#pragma unroll
        for (int off = 8; off; off >>= 1) {
          s += __shfl_xor(s, off);
          s2 += __shfl_xor(s2, off);
        }
        float m = s * (1.0f / 64.0f);
        float var = fmaxf(s2 * (1.0f / 64.0f) - m * m, 0.f);
        float rs = rsqrtf(var + 1e-5f);
        int row = mBase + wr * 64 + i * 16 + grp * 4 + r;
#pragma unroll
        for (int j = 0; j < 4; ++j) {
          int col = nBase + wc * 64 + j * 16 + r16;
          float v = acc[i][j][r];
          if (doNorm) v = (v - m) * rs;
          o16[(size_t)row * ldo + col] = f2h(v);
        }
      }
    }
    return;
  }

#pragma unroll
  for (int i = 0; i < 4; ++i) {
#pragma unroll
    for (int j = 0; j < 4; ++j) {
#pragma unroll
      for (int r = 0; r < 4; ++r) {
        int row = mBase + wr * 64 + i * 16 + grp * 4 + r;
        int col = nBase + wc * 64 + j * 16 + r16;
        float v = acc[i][j][r];
        if constexpr (MODE == 0) {
          v = (v + bias[col]) * 22.627416997969522f;
          int n = row & (SEQ - 1);
          int k2 = col >> 1;
          float ang = (float)n * expf((float)k2 * -0.03597789207803197f);
          v += (col & 1) ? cosf(ang) : sinf(ang);
          out32[(size_t)row * HID + col] = v;
        } else if constexpr (MODE == 2) {
          v = v * ascale + bias[col] + Hin[(size_t)row * HID + col];
          out32[(size_t)row * HID + col] = v;
          o16[(size_t)row * HID + col] = f2h(v * RSCLI);
        } else if constexpr (MODE == 7) {
          v = v * RSCL + bias[col];
          out32[(size_t)(row >> 12) * (128 * 4096) + (size_t)col * SEQ + (row & 4095)] = v;
        } else {  // MODE 5: gated
          float a = v * RSCL + bias[col];
          float c2 = acc2[i][j][r] * RSCL + bias[2048 + col];
          float gl = 0.5f * a * (1.0f + erff(a * 0.7071067811865475f));
          o16[(size_t)row * ldo + col] = f2h(gl * c2 * RSCLI);
        }
      }
    }
  }
}

// ---------------------------------------------------------------------------
extern "C" void kernel_launch(void* const* d_in, const int* in_sizes, int n_in,
                              void* d_out, int out_size, void* d_ws, size_t ws_size,
                              hipStream_t stream) {
  const float* x    = (const float*)d_in[0];
  const float* Wemb = (const float*)d_in[1];
  const float* bemb = (const float*)d_in[2];
  const float* lng  = (const float*)d_in[3];
  const float* lnb  = (const float*)d_in[4];
  const float* Wqkv = (const float*)d_in[5];
  const float* Wout = (const float*)d_in[6];
  const float* bout = (const float*)d_in[7];
  const float* W1   = (const float*)d_in[8];
  const float* b1   = (const float*)d_in[9];
  const float* W2   = (const float*)d_in[10];
  const float* b2   = (const float*)d_in[11];
  const float* Wd   = (const float*)d_in[12];
  const float* bd   = (const float*)d_in[13];

  char* p = (char*)d_ws;
  auto alloc = [&](size_t bytes) {
    char* r = p;
    p += (bytes + 255) & ~(size_t)255;
    return r;
  };
  // ---- total ~167MB (limit ~256MiB) ----
  u16* WembT = (u16*)alloc((size_t)512 * 128 * 2);
  u16* WqkvT = (u16*)alloc((size_t)6 * 1536 * 512 * 2);
  u16* WoutT = (u16*)alloc((size_t)6 * 512 * 512 * 2);
  u16* W1T   = (u16*)alloc((size_t)6 * 4096 * 512 * 2);
  u16* W2T   = (u16*)alloc((size_t)6 * 512 * 2048 * 2);
  u16* WdT   = (u16*)alloc((size_t)128 * 512 * 2);
  float* H   = (float*)alloc((size_t)NTOK * 512 * 4);     // 32MB residual f32
  u16* HB    = (u16*)alloc((size_t)NTOK * 512 * 2);       // fp16(h/256)
  float* DOTSP = (float*)alloc((size_t)8 * 32 * 4096 * 4);
  float* DOTS  = (float*)alloc((size_t)32 * 4096 * 4);
  // Union region U (64 MiB), sequential lifetimes:
  //  pre-loop: XP@0 (4MB)
  //  attn:  Y@0 (16MB), QKV@16Mi (48MB); O@0 after Y dead
  //  mlp:   F@0 (64MB)
  char* U = alloc((size_t)64 * 1024 * 1024);
  const size_t MI = 1024 * 1024;
  u16* XP  = (u16*)U;
  u16* Y   = (u16*)U;
  u16* QKV = (u16*)(U + 16 * MI);
  u16* O   = (u16*)U;
  u16* F   = (u16*)U;

  // weights -> fp16, transposed to [N][K]
  k_transpose<<<dim3(2, 8, 1),  256, 0, stream>>>(Wemb, WembT, 128, 512);
  k_transpose<<<dim3(8, 24, 6), 256, 0, stream>>>(Wqkv, WqkvT, 512, 1536);
  k_transpose<<<dim3(8, 8, 6),  256, 0, stream>>>(Wout, WoutT, 512, 512);
  k_transpose<<<dim3(8, 64, 6), 256, 0, stream>>>(W1, W1T, 512, 4096);
  k_transpose<<<dim3(32, 8, 6), 256, 0, stream>>>(W2, W2T, 2048, 512);
  k_transpose<<<dim3(8, 2, 1),  256, 0, stream>>>(Wd, WdT, 512, 128);

  k_packx<<<8192, 256, 0, stream>>>(x, XP);
  // embed: H = (XP @ Wemb + b)*sqrt(512) + posenc
  k_gemm<0><<<dim3(4, 128), 256, 0, stream>>>(XP, WembT, nullptr, 128, bemb,
      nullptr, 1.f, H, nullptr, 0);

  for (int i = 0; i < 6; ++i) {
    k_ln<<<4096, 256, 0, stream>>>(H, lng + i * 512, lnb + i * 512, Y);
    k_gemm<1><<<dim3(12, 128), 256, 0, stream>>>(Y,
        WqkvT + (size_t)i * 1536 * 512, nullptr, 512,
        nullptr, nullptr, 1.f, nullptr, QKV, 1536);
    k_dots<<<dim3(8, 32), 256, 0, stream>>>(QKV, DOTSP);
    k_reddots<<<512, 256, 0, stream>>>(DOTSP, DOTS);
    k_ov<<<dim3(64, 32), 256, 0, stream>>>(QKV, DOTS, O);
    k_gemm<2><<<dim3(4, 128), 256, 0, stream>>>(O,
        WoutT + (size_t)i * 512 * 512, nullptr, 512,
        bout + i * 512, H, 1.f, H, HB, 512);
    k_gemm<5><<<dim3(16, 128), 256, 0, stream>>>(HB,
        W1T + (size_t)i * 4096 * 512,
        W1T + (size_t)i * 4096 * 512 + (size_t)2048 * 512, 512,
        b1 + i * 4096, nullptr, 1.f, nullptr, F, 2048);
    k_gemm<2><<<dim3(4, 128), 256, 0, stream>>>(F,
        W2T + (size_t)i * 512 * 2048, nullptr, 2048,
        b2 + i * 512, H, RSCL, H, HB, 512);
  }
  // final: out[b, col*4096+n] = h @ Wd + bd
  k_gemm<7><<<dim3(1, 128), 256, 0, stream>>>(HB, WdT, nullptr, 512, bd,
      nullptr, 1.f, (float*)d_out, nullptr, 0);
}